// Round 5
// baseline (56.741 us; speedup 1.0000x reference)
//
#include <hip/hip_runtime.h>
#include <math.h>

#define BS 16
#define NQ 100
#define NPTS 25
#define VOC 96
#define NC 97              // VOC+1 classes incl. padding
#define MAXLEN 25
#define NGT 32
#define EDIM 300
#define NCOL 512           // BS*NGT
#define NDIM 50            // NPTS*2
#define PBLK 512           // pred/assemble block count (reps cover 1600)

// ---------------- workspace layout (floats) ----------------
#define WS_GRAM 0                       // 97*96 = 9312 (row 96 = zeros)
#define WS_LOGP (WS_GRAM + NC * VOC)    // 1600*96
#define WS_CC   (WS_LOGP + 1600 * VOC)  // 1600
#define WS_TGTT (WS_CC + 1600)          // 50*512
#define WS_STAT (WS_TGTT + NDIM * NCOL) // 512*97: [pair][0..95]=ts, [96]=neg_ent

// ================= K1: gram table (96 blocks) + tgtT transpose (all 100) =================
__global__ __launch_bounds__(256) void k1_kernel(const float* __restrict__ cen,
                                                 const float* __restrict__ tgt_pts,
                                                 float* __restrict__ gram,
                                                 float* __restrict__ tgtT) {
    __shared__ float row[EDIM];
    __shared__ float red[256];
    int blk = blockIdx.x, tid = threadIdx.x;

    // transpose share: grid is exactly 100 blocks * 256 = 25600 elems
    int gidx = blk * 256 + tid;
    int k = gidx >> 9, j = gidx & 511;
    tgtT[gidx] = tgt_pts[(size_t)j * NDIM + k];

    if (blk == 0 && tid < VOC) gram[VOC * VOC + tid] = 0.f;   // zero pad row
    if (blk >= VOC) return;    // blocks 96..99: transpose only

    for (int i = tid; i < EDIM; i += 256) row[i] = cen[blk * EDIM + i];
    __syncthreads();
    float val = -INFINITY;
    if (tid < VOC) {
        float a = 0.f;
        const float* c = cen + (size_t)tid * EDIM;
        for (int i = 0; i < EDIM; ++i) a += row[i] * c[i];
        val = a * 0.05773502691896258f;       // 1/sqrt(300)
    }
    red[tid] = val;
    __syncthreads();
    for (int s = 128; s; s >>= 1) { if (tid < s) red[tid] = fmaxf(red[tid], red[tid + s]); __syncthreads(); }
    float m = red[0];
    __syncthreads();
    float e = (tid < VOC) ? expf(val - m) : 0.f;
    red[tid] = e;
    __syncthreads();
    for (int s = 128; s; s >>= 1) { if (tid < s) red[tid] += red[tid + s]; __syncthreads(); }
    if (tid < VOC) gram[blk * VOC + tid] = e / red[0];
}

// ================= K2: pred (blocks 0..511) | tgt-stats (blocks 512..639) =================
__global__ __launch_bounds__(256) void k2_kernel(
        const float* __restrict__ logits1,   // (1600,25,1)
        const float* __restrict__ tlogits,   // (1600,25,97)
        const int*   __restrict__ texts,     // (512,25)
        const float* __restrict__ gram,      // (97,96), row 96 zeros
        float* __restrict__ logp, float* __restrict__ cc,
        float* __restrict__ stat) {
    __shared__ float sm[NPTS * NC];          // 2425
    int blk = blockIdx.x, tid = threadIdx.x;
    int wave = tid >> 6, lane = tid & 63;

    if (blk < PBLK) {
        // ---- pred: units u = rep*512 + blk
        for (int rep = 0; rep < 4; ++rep) {
            int u = rep * PBLK + blk;
            if (u >= 1600) break;            // blk-uniform
            const float* src = tlogits + (size_t)u * NPTS * NC;
            for (int i = tid; i < NPTS * NC; i += 256) sm[i] = src[i];
            __syncthreads();
            for (int p = wave; p < NPTS; p += 4) {
                float* r = sm + p * NC;
                float x0 = r[lane];
                float x1 = (lane < 33) ? r[64 + lane] : -INFINITY;
                float m = fmaxf(x0, x1);
                for (int o = 32; o; o >>= 1) m = fmaxf(m, __shfl_xor(m, o));
                float e0 = expf(x0 - m);
                float e1 = (lane < 33) ? expf(x1 - m) : 0.f;
                float s = e0 + e1;
                for (int o = 32; o; o >>= 1) s += __shfl_xor(s, o);
                float inv = 1.f / s;
                r[lane] = e0 * inv;               // normalized prob back to LDS
                if (lane < 33) r[64 + lane] = e1 * inv;
            }
            __syncthreads();
            if (tid < VOC) {
                float acc = 0.f;
#pragma unroll
                for (int p = 0; p < NPTS; ++p) acc += sm[p * NC + tid];
                logp[(size_t)u * VOC + tid] = logf(fmaxf(acc * 0.04f, 1e-6f));
            }
            if (wave == 3) {
                float sig = 0.f;
                if (lane < NPTS) { float x = logits1[u * NPTS + lane]; sig = 1.f / (1.f + expf(-x)); }
                for (int o = 32; o; o >>= 1) sig += __shfl_xor(sig, o);
                if (lane == 0) {
                    float prob = sig * 0.04f;
                    float negc = 0.75f * prob * prob * (-logf(1.f - prob + 1e-8f));
                    float posc = 0.25f * (1.f - prob) * (1.f - prob) * (-logf(prob + 1e-8f));
                    cc[u] = posc - negc;
                }
            }
            __syncthreads();
        }
    } else {
        // ---- tgt-stats: 128 blocks x 4 waves, pair = (blk-512)*4 + wave, once per pair
        int pair = (blk - PBLK) * 4 + wave;  // 0..511
        const int* tx = texts + pair * MAXLEN;
        float a0 = 0.f, a1 = 0.f;
        int len = 0;
#pragma unroll
        for (int l = 0; l < MAXLEN; ++l) {
            int v = tx[l];                   // wave-uniform scalar load
            len += (v != VOC);
            const float* gr = gram + v * VOC;   // row 96 = zeros (branch-free)
            a0 += gr[lane];
            a1 += (lane < 32) ? gr[64 + lane] : 0.f;
        }
        float dinv = 1.f / (float)(len > 0 ? len : 1);
        float t0 = fmaxf(a0 * dinv, 1e-6f);
        float t1 = (lane < 32) ? fmaxf(a1 * dinv, 1e-6f) : 0.f;
        float s = t0 + t1;
        for (int o = 32; o; o >>= 1) s += __shfl_xor(s, o);
        float inv = 1.f / s;
        float ts0 = t0 * inv, ts1 = t1 * inv;
        float c0 = ts0 * logf(ts0);
        float c1 = (lane < 32) ? ts1 * logf(ts1) : 0.f;
        float ent = c0 + c1;
        for (int o = 32; o; o >>= 1) ent += __shfl_xor(ent, o);
        float* dst = stat + (size_t)pair * NC;
        dst[lane] = len ? ts0 : 0.f;
        if (lane < 32) dst[64 + lane] = len ? ts1 : 0.f;
        if (lane == 0) dst[VOC] = len ? ent : 100.f;
    }
}

// ================= K3: assemble rows r = rep*512 + blk (3-4 rows/block) =================
__global__ __launch_bounds__(256) void k3_kernel(
        const float* __restrict__ pred_pts,  // (1600,50)
        const float* __restrict__ tgtT,      // (50,512)
        const float* __restrict__ logp,      // (1600,96)
        const float* __restrict__ cc,        // (1600,)
        const float* __restrict__ stat,      // (512,97)
        float* __restrict__ out) {           // (1600,512)
    __shared__ float sm[4080];
    float* sA    = sm;              // 3104 = 32*97
    float* lp4   = sm + 3104;       // 384
    float* pp4   = sm + 3488;       // 200
    float* cc4   = sm + 3688;       // 4
    float* ct4   = sm + 3692;       // 128
    float* spart = sm + 3820;       // 256
    int blk = blockIdx.x, tid = threadIdx.x;

    for (int i = tid; i < 4 * VOC; i += 256) {
        int rep = i / VOC, c = i - rep * VOC;
        int r = rep * PBLK + blk;
        lp4[i] = (r < 1600) ? logp[(size_t)r * VOC + c] : 0.f;
    }
    if (tid < 4 * NDIM) {
        int rep = tid / NDIM, k = tid - rep * NDIM;
        int r = rep * PBLK + blk;
        pp4[tid] = (r < 1600) ? pred_pts[(size_t)r * NDIM + k] : 0.f;
    }
    if (tid < 4) {
        int r = tid * PBLK + blk;
        cc4[tid] = (r < 1600) ? cc[r] : 0.f;
    }
    __syncthreads();

    // ---- KL per rep: stage stat[b] then 256-thread distributed dot
    for (int rep = 0; rep < 4; ++rep) {
        int r = rep * PBLK + blk;
        if (r >= 1600) break;                // blk-uniform
        int b = r / NQ;
        for (int i = tid; i < NGT * NC; i += 256) sA[i] = stat[(size_t)b * NGT * NC + i];
        __syncthreads();
        {
            int g = tid >> 3, sub = tid & 7;     // 32 g's x 8 partials
            const float* rw = sA + g * NC + sub * 12;
            const float* L  = lp4 + rep * VOC + sub * 12;
            float d = 0.f;
#pragma unroll
            for (int jj = 0; jj < 12; ++jj) d += L[jj] * rw[jj];
            spart[tid] = d;
        }
        __syncthreads();
        if (tid < NGT) {
            float s = 0.f;
#pragma unroll
            for (int jj = 0; jj < 8; ++jj) s += spart[tid * 8 + jj];
            ct4[rep * NGT + tid] = fmaxf(sA[tid * NC + VOC] - s, 0.f);
        }
        __syncthreads();
    }

    // ---- joint L1 sweep: one tgtT pass for all 4 rows, 2 cols/thread
    float a0[4], a1[4];
#pragma unroll
    for (int rp = 0; rp < 4; ++rp) { a0[rp] = 0.f; a1[rp] = 0.f; }
#pragma unroll 5
    for (int k = 0; k < NDIM; ++k) {
        float tv0 = tgtT[(k << 9) + tid];
        float tv1 = tgtT[(k << 9) + 256 + tid];
#pragma unroll
        for (int rp = 0; rp < 4; ++rp) {
            float p = pp4[rp * NDIM + k];
            a0[rp] += fabsf(p - tv0);
            a1[rp] += fabsf(p - tv1);
        }
    }

    int g = tid & 31, gb = tid >> 5;
#pragma unroll
    for (int rep = 0; rep < 4; ++rep) {
        int r = rep * PBLK + blk;
        if (r >= 1600) break;
        int b = r / NQ;
        float cv = cc4[rep];
        float t0 = (gb == b)     ? ct4[rep * NGT + g] : 0.f;
        float t1 = (8 + gb == b) ? ct4[rep * NGT + g] : 0.f;
        out[(size_t)r * NCOL + tid]       = cv + a0[rep] + t0;
        out[(size_t)r * NCOL + 256 + tid] = cv + a1[rep] + t1;
    }
}

extern "C" void kernel_launch(void* const* d_in, const int* in_sizes, int n_in,
                              void* d_out, int out_size, void* d_ws, size_t ws_size,
                              hipStream_t stream) {
    const float* pred_logits      = (const float*)d_in[0];
    const float* pred_ctrl_points = (const float*)d_in[1];
    const float* pred_text_logits = (const float*)d_in[2];
    const float* tgt_ctrl_points  = (const float*)d_in[3];
    const int*   target_texts     = (const int*)d_in[4];
    const float* centroids        = (const float*)d_in[5];
    float* out = (float*)d_out;
    float* ws  = (float*)d_ws;

    float* gram = ws + WS_GRAM;
    float* logp = ws + WS_LOGP;
    float* cc   = ws + WS_CC;
    float* tgtT = ws + WS_TGTT;
    float* stat = ws + WS_STAT;

    k1_kernel<<<100, 256, 0, stream>>>(centroids, tgt_ctrl_points, gram, tgtT);
    k2_kernel<<<PBLK + 128, 256, 0, stream>>>(pred_logits, pred_text_logits,
                                              target_texts, gram, logp, cc, stat);
    k3_kernel<<<PBLK, 256, 0, stream>>>(pred_ctrl_points, tgtT, logp, cc, stat, out);
}

// Round 6
// 43.576 us; speedup vs baseline: 1.3021x; 1.3021x over previous
//
#include <hip/hip_runtime.h>
#include <math.h>

#define BS 16
#define NQ 100
#define NPTS 25
#define VOC 96
#define NC 97              // VOC+1 classes incl. padding
#define MAXLEN 25
#define NGT 32
#define EDIM 300
#define NCOL 512           // BS*NGT
#define NDIM 50            // NPTS*2
#define PRED_BLKS 1600
#define STAT_BLKS 256      // 2 waves/block, 1 pair/wave -> 512 pairs
#define ABLK 512           // assemble blocks (4 rows each)

// ---------------- workspace layout (floats) ----------------
#define WS_GRAM 0                       // 97*96 = 9312 (row 96 = zeros)
#define WS_LOGP (WS_GRAM + NC * VOC)    // 1600*96
#define WS_CC   (WS_LOGP + 1600 * VOC)  // 1600
#define WS_TGTT (WS_CC + 1600)          // 50*512
#define WS_STAT (WS_TGTT + NDIM * NCOL) // 512*97: [pair][0..95]=ts, [96]=neg_ent

// ================= K1: gram table (96 blocks) + tgtT transpose (all 100) =================
__global__ __launch_bounds__(256) void k1_kernel(const float* __restrict__ cen,
                                                 const float* __restrict__ tgt_pts,
                                                 float* __restrict__ gram,
                                                 float* __restrict__ tgtT) {
    __shared__ float row[EDIM];
    __shared__ float red[256];
    int blk = blockIdx.x, tid = threadIdx.x;

    // transpose share: grid is exactly 100 blocks * 256 = 25600 elems
    int gidx = blk * 256 + tid;
    int k = gidx >> 9, j = gidx & 511;
    tgtT[gidx] = tgt_pts[(size_t)j * NDIM + k];

    if (blk == 0 && tid < VOC) gram[VOC * VOC + tid] = 0.f;   // zero pad row
    if (blk >= VOC) return;    // blocks 96..99: transpose only

    for (int i = tid; i < EDIM; i += 256) row[i] = cen[blk * EDIM + i];
    __syncthreads();
    float val = -INFINITY;
    if (tid < VOC) {
        float a = 0.f;
        const float* c = cen + (size_t)tid * EDIM;
        for (int i = 0; i < EDIM; ++i) a += row[i] * c[i];
        val = a * 0.05773502691896258f;       // 1/sqrt(300)
    }
    red[tid] = val;
    __syncthreads();
    for (int s = 128; s; s >>= 1) { if (tid < s) red[tid] = fmaxf(red[tid], red[tid + s]); __syncthreads(); }
    float m = red[0];
    __syncthreads();
    float e = (tid < VOC) ? expf(val - m) : 0.f;
    red[tid] = e;
    __syncthreads();
    for (int s = 128; s; s >>= 1) { if (tid < s) red[tid] += red[tid + s]; __syncthreads(); }
    if (tid < VOC) gram[blk * VOC + tid] = e / red[0];
}

// ================= K2: pred (blocks 0..1599, 1 unit each) | tgt-stats (1600..1855) =================
__global__ __launch_bounds__(128) void k2_kernel(
        const float* __restrict__ logits1,   // (1600,25,1)
        const float* __restrict__ tlogits,   // (1600,25,97)
        const int*   __restrict__ texts,     // (512,25)
        const float* __restrict__ gram,      // (97,96), row 96 zeros
        float* __restrict__ logp, float* __restrict__ cc,
        float* __restrict__ stat) {
    __shared__ float sm[NPTS * NC];          // 2425
    int blk = blockIdx.x, tid = threadIdx.x;
    int wave = tid >> 6, lane = tid & 63;

    if (blk < PRED_BLKS) {
        // ---- pred unit u = blk: per-point softmax -> mean prob -> logp; focal cost
        int u = blk;
        const float* src = tlogits + (size_t)u * NPTS * NC;
        for (int i = tid; i < NPTS * NC; i += 128) sm[i] = src[i];
        __syncthreads();
        for (int p = wave; p < NPTS; p += 2) {
            float* r = sm + p * NC;
            float x0 = r[lane];
            float x1 = (lane < 33) ? r[64 + lane] : -INFINITY;
            float m = fmaxf(x0, x1);
            for (int o = 32; o; o >>= 1) m = fmaxf(m, __shfl_xor(m, o));
            float e0 = expf(x0 - m);
            float e1 = (lane < 33) ? expf(x1 - m) : 0.f;
            float s = e0 + e1;
            for (int o = 32; o; o >>= 1) s += __shfl_xor(s, o);
            float inv = 1.f / s;
            r[lane] = e0 * inv;               // normalized prob back to LDS
            if (lane < 33) r[64 + lane] = e1 * inv;
        }
        __syncthreads();
        if (tid < VOC) {
            float acc = 0.f;
#pragma unroll
            for (int p = 0; p < NPTS; ++p) acc += sm[p * NC + tid];
            logp[(size_t)u * VOC + tid] = logf(fmaxf(acc * 0.04f, 1e-6f));
        }
        if (wave == 1) {
            float sig = 0.f;
            if (lane < NPTS) { float x = logits1[u * NPTS + lane]; sig = 1.f / (1.f + expf(-x)); }
            for (int o = 32; o; o >>= 1) sig += __shfl_xor(sig, o);
            if (lane == 0) {
                float prob = sig * 0.04f;
                float negc = 0.75f * prob * prob * (-logf(1.f - prob + 1e-8f));
                float posc = 0.25f * (1.f - prob) * (1.f - prob) * (-logf(prob + 1e-8f));
                cc[u] = posc - negc;
            }
        }
    } else {
        // ---- tgt-stats: pair = (blk-1600)*2 + wave, once per pair, branch-free
        int pair = (blk - PRED_BLKS) * 2 + wave;   // 0..511
        const int* tx = texts + pair * MAXLEN;
        float a0 = 0.f, a1 = 0.f;
        int len = 0;
#pragma unroll
        for (int l = 0; l < MAXLEN; ++l) {
            int v = tx[l];                   // wave-uniform scalar load
            len += (v != VOC);
            const float* gr = gram + v * VOC;   // row 96 = zeros (branch-free)
            a0 += gr[lane];
            a1 += (lane < 32) ? gr[64 + lane] : 0.f;
        }
        float dinv = 1.f / (float)(len > 0 ? len : 1);
        float t0 = fmaxf(a0 * dinv, 1e-6f);
        float t1 = (lane < 32) ? fmaxf(a1 * dinv, 1e-6f) : 0.f;
        float s = t0 + t1;
        for (int o = 32; o; o >>= 1) s += __shfl_xor(s, o);
        float inv = 1.f / s;
        float ts0 = t0 * inv, ts1 = t1 * inv;
        float c0 = ts0 * logf(ts0);
        float c1 = (lane < 32) ? ts1 * logf(ts1) : 0.f;
        float ent = c0 + c1;
        for (int o = 32; o; o >>= 1) ent += __shfl_xor(ent, o);
        float* dst = stat + (size_t)pair * NC;
        dst[lane] = len ? ts0 : 0.f;
        if (lane < 32) dst[64 + lane] = len ? ts1 : 0.f;
        if (lane == 0) dst[VOC] = len ? ent : 100.f;
    }
}

// ================= K3: assemble rows r = rep*512 + blk (3-4 rows/block) =================
__global__ __launch_bounds__(256) void k3_kernel(
        const float* __restrict__ pred_pts,  // (1600,50)
        const float* __restrict__ tgtT,      // (50,512)
        const float* __restrict__ logp,      // (1600,96)
        const float* __restrict__ cc,        // (1600,)
        const float* __restrict__ stat,      // (512,97)
        float* __restrict__ out) {           // (1600,512)
    __shared__ float sm[4080];
    float* sA    = sm;              // 3104 = 32*97
    float* lp4   = sm + 3104;       // 384
    float* pp4   = sm + 3488;       // 200
    float* cc4   = sm + 3688;       // 4
    float* ct4   = sm + 3692;       // 128
    float* spart = sm + 3820;       // 256
    int blk = blockIdx.x, tid = threadIdx.x;

    for (int i = tid; i < 4 * VOC; i += 256) {
        int rep = i / VOC, c = i - rep * VOC;
        int r = rep * ABLK + blk;
        lp4[i] = (r < 1600) ? logp[(size_t)r * VOC + c] : 0.f;
    }
    if (tid < 4 * NDIM) {
        int rep = tid / NDIM, k = tid - rep * NDIM;
        int r = rep * ABLK + blk;
        pp4[tid] = (r < 1600) ? pred_pts[(size_t)r * NDIM + k] : 0.f;
    }
    if (tid < 4) {
        int r = tid * ABLK + blk;
        cc4[tid] = (r < 1600) ? cc[r] : 0.f;
    }
    __syncthreads();

    // ---- KL per rep: stage stat[b] then 256-thread distributed dot
    for (int rep = 0; rep < 4; ++rep) {
        int r = rep * ABLK + blk;
        if (r >= 1600) break;                // blk-uniform
        int b = r / NQ;
        for (int i = tid; i < NGT * NC; i += 256) sA[i] = stat[(size_t)b * NGT * NC + i];
        __syncthreads();
        {
            int g = tid >> 3, sub = tid & 7;     // 32 g's x 8 partials
            const float* rw = sA + g * NC + sub * 12;
            const float* L  = lp4 + rep * VOC + sub * 12;
            float d = 0.f;
#pragma unroll
            for (int jj = 0; jj < 12; ++jj) d += L[jj] * rw[jj];
            spart[tid] = d;
        }
        __syncthreads();
        if (tid < NGT) {
            float s = 0.f;
#pragma unroll
            for (int jj = 0; jj < 8; ++jj) s += spart[tid * 8 + jj];
            ct4[rep * NGT + tid] = fmaxf(sA[tid * NC + VOC] - s, 0.f);
        }
        __syncthreads();
    }

    // ---- joint L1 sweep: one tgtT pass for all 4 rows, 2 cols/thread
    float a0[4], a1[4];
#pragma unroll
    for (int rp = 0; rp < 4; ++rp) { a0[rp] = 0.f; a1[rp] = 0.f; }
#pragma unroll 5
    for (int k = 0; k < NDIM; ++k) {
        float tv0 = tgtT[(k << 9) + tid];
        float tv1 = tgtT[(k << 9) + 256 + tid];
#pragma unroll
        for (int rp = 0; rp < 4; ++rp) {
            float p = pp4[rp * NDIM + k];
            a0[rp] += fabsf(p - tv0);
            a1[rp] += fabsf(p - tv1);
        }
    }

    int g = tid & 31, gb = tid >> 5;
#pragma unroll
    for (int rep = 0; rep < 4; ++rep) {
        int r = rep * ABLK + blk;
        if (r >= 1600) break;
        int b = r / NQ;
        float cv = cc4[rep];
        float t0 = (gb == b)     ? ct4[rep * NGT + g] : 0.f;
        float t1 = (8 + gb == b) ? ct4[rep * NGT + g] : 0.f;
        out[(size_t)r * NCOL + tid]       = cv + a0[rep] + t0;
        out[(size_t)r * NCOL + 256 + tid] = cv + a1[rep] + t1;
    }
}

extern "C" void kernel_launch(void* const* d_in, const int* in_sizes, int n_in,
                              void* d_out, int out_size, void* d_ws, size_t ws_size,
                              hipStream_t stream) {
    const float* pred_logits      = (const float*)d_in[0];
    const float* pred_ctrl_points = (const float*)d_in[1];
    const float* pred_text_logits = (const float*)d_in[2];
    const float* tgt_ctrl_points  = (const float*)d_in[3];
    const int*   target_texts     = (const int*)d_in[4];
    const float* centroids        = (const float*)d_in[5];
    float* out = (float*)d_out;
    float* ws  = (float*)d_ws;

    float* gram = ws + WS_GRAM;
    float* logp = ws + WS_LOGP;
    float* cc   = ws + WS_CC;
    float* tgtT = ws + WS_TGTT;
    float* stat = ws + WS_STAT;

    k1_kernel<<<100, 256, 0, stream>>>(centroids, tgt_ctrl_points, gram, tgtT);
    k2_kernel<<<PRED_BLKS + STAT_BLKS, 128, 0, stream>>>(pred_logits, pred_text_logits,
                                                         target_texts, gram, logp, cc, stat);
    k3_kernel<<<ABLK, 256, 0, stream>>>(pred_ctrl_points, tgtT, logp, cc, stat, out);
}

// Round 7
// 35.981 us; speedup vs baseline: 1.5770x; 1.2111x over previous
//
#include <hip/hip_runtime.h>
#include <math.h>

#define BS 16
#define NQ 100
#define NPTS 25
#define VOC 96
#define NC 97              // VOC+1 classes incl. padding
#define MAXLEN 25
#define NGT 32
#define EDIM 300
#define NCOL 512           // BS*NGT
#define NDIM 50            // NPTS*2
#define RPB 10             // rows per assemble block (divides 100)

// ---------------- workspace layout (floats) ----------------
#define WS_GRAM 0                       // 97*96 = 9312 (row 96 = zeros)
#define WS_LOGP (WS_GRAM + NC * VOC)    // 1600*96
#define WS_CC   (WS_LOGP + 1600 * VOC)  // 1600
#define WS_TGTT (WS_CC + 1600)          // 50*512

#define GRAM_BLKS VOC              // 96
#define PRED_BLKS 1600
#define TR_BLKS 200                // 200*128 = 25600
#define K1_BLKS (GRAM_BLKS + PRED_BLKS + TR_BLKS)

// ---- K1: role-split: gram rows | pred (logp + focal) | tgt-point transpose
__global__ __launch_bounds__(128) void k1_kernel(
        const float* __restrict__ logits1,   // (1600,25,1)
        const float* __restrict__ tlogits,   // (1600,25,97)
        const float* __restrict__ cen,       // (96,300)
        const float* __restrict__ tgt_pts,   // (512,50)
        float* __restrict__ gram, float* __restrict__ logp,
        float* __restrict__ cost_class, float* __restrict__ tgtT) {
    __shared__ float smem[NPTS * NC];        // 2425 floats; reused per role
    int blk = blockIdx.x, tid = threadIdx.x;
    int wave = tid >> 6, lane = tid & 63;

    if (blk < GRAM_BLKS) {
        // ---- gram row v = blk: softmax_c( dot(cen[v],cen[c]) / sqrt(EDIM) )
        float* row = smem;                   // 300
        float* red = smem + 512;             // 128
        for (int k = tid; k < EDIM; k += 128) row[k] = cen[blk * EDIM + k];
        if (blk == 0 && tid < VOC) gram[VOC * VOC + tid] = 0.f;   // zero pad row
        __syncthreads();
        float val = -INFINITY;
        if (tid < VOC) {
            float acc = 0.f;
            const float* c = cen + (size_t)tid * EDIM;
            for (int k = 0; k < EDIM; ++k) acc += row[k] * c[k];
            val = acc * 0.05773502691896258f;   // 1/sqrt(300)
        }
        red[tid] = val;
        __syncthreads();
        for (int s = 64; s; s >>= 1) { if (tid < s) red[tid] = fmaxf(red[tid], red[tid + s]); __syncthreads(); }
        float m = red[0];
        __syncthreads();
        float e = (tid < VOC) ? expf(val - m) : 0.f;
        red[tid] = e;
        __syncthreads();
        for (int s = 64; s; s >>= 1) { if (tid < s) red[tid] += red[tid + s]; __syncthreads(); }
        if (tid < VOC) gram[blk * VOC + tid] = e / red[0];
    } else if (blk < GRAM_BLKS + PRED_BLKS) {
        // ---- pred unit bq: per-point softmax -> mean prob -> logp; focal cost
        int bq = blk - GRAM_BLKS;
        const float* src = tlogits + (size_t)bq * NPTS * NC;
        for (int i = tid; i < NPTS * NC; i += 128) smem[i] = src[i];
        __syncthreads();
        for (int p = wave; p < NPTS; p += 2) {
            float* r = smem + p * NC;
            float x0 = r[lane];
            float x1 = (lane < 33) ? r[64 + lane] : -INFINITY;
            float m = fmaxf(x0, x1);
            for (int o = 32; o; o >>= 1) m = fmaxf(m, __shfl_xor(m, o));
            float e0 = expf(x0 - m);
            float e1 = (lane < 33) ? expf(x1 - m) : 0.f;
            float s = e0 + e1;
            for (int o = 32; o; o >>= 1) s += __shfl_xor(s, o);
            float inv = 1.f / s;
            r[lane] = e0 * inv;                       // normalized prob back
            if (lane < 33) r[64 + lane] = e1 * inv;
        }
        __syncthreads();
        if (tid < VOC) {
            float acc = 0.f;
#pragma unroll
            for (int p = 0; p < NPTS; ++p) acc += smem[p * NC + tid];
            logp[(size_t)bq * VOC + tid] = logf(fmaxf(acc * 0.04f, 1e-6f));
        }
        if (wave == 0) {
            float sig = 0.f;
            if (lane < NPTS) { float x = logits1[bq * NPTS + lane]; sig = 1.f / (1.f + expf(-x)); }
            for (int o = 32; o; o >>= 1) sig += __shfl_xor(sig, o);
            if (lane == 0) {
                float prob = sig * 0.04f;
                float negc = 0.75f * prob * prob * (-logf(1.f - prob + 1e-8f));
                float posc = 0.25f * (1.f - prob) * (1.f - prob) * (-logf(prob + 1e-8f));
                cost_class[bq] = posc - negc;
            }
        }
    } else {
        // ---- transpose tgt points (512,50) -> (50,512)
        int g = (blk - GRAM_BLKS - PRED_BLKS) * 128 + tid;   // < 25600 exactly
        int k = g / NCOL;
        int j = g - k * NCOL;
        tgtT[g] = tgt_pts[(size_t)j * NDIM + k];
    }
}

// ================= K2: fused stats + assemble =================
// 160 blocks x 512 thr; block owns rows r0 = blk*10 .. r0+9, all in image b = blk/10.
__global__ __launch_bounds__(512) void k2_kernel(
        const float* __restrict__ pred_pts,  // (1600,50)
        const float* __restrict__ tgtT,      // (50,512)
        const float* __restrict__ gram,      // (97,96), row 96 zeros
        const int*   __restrict__ texts,     // (512,25)
        const float* __restrict__ logp,      // (1600,96)
        const float* __restrict__ cc,        // (1600,)
        float* __restrict__ out) {           // (1600,512)
    __shared__ float s_stat[NGT][NC];        // ts[0..95], [96]=neg_ent (stride 97: conflict-free)
    __shared__ float s_lp[RPB][VOC];
    __shared__ float s_pp[RPB][NDIM];
    __shared__ float s_cc[RPB];
    __shared__ float s_ct[RPB][NGT];
    __shared__ int   s_tex[NGT * MAXLEN];    // 800

    int blk = blockIdx.x, tid = threadIdx.x;
    int wave = tid >> 6, lane = tid & 63;
    int r0 = blk * RPB;
    int b = blk / (NQ / RPB);                // = r0/100

    for (int i = tid; i < NGT * MAXLEN; i += 512) s_tex[i] = texts[b * NGT * MAXLEN + i];
    for (int i = tid; i < RPB * VOC; i += 512) s_lp[i / VOC][i % VOC] = logp[(size_t)r0 * VOC + i];
    if (tid < RPB * NDIM) s_pp[tid / NDIM][tid % NDIM] = pred_pts[(size_t)r0 * NDIM + tid];
    if (tid < RPB) s_cc[tid] = cc[r0 + tid];
    __syncthreads();

    // ---- stats: 8 waves x 4 pairs, branch-free gram gathers
    for (int j = 0; j < NGT / 8; ++j) {
        int g = wave * 4 + j;
        const int* tx = s_tex + g * MAXLEN;
        float a0 = 0.f, a1 = 0.f;
        int len = 0;
#pragma unroll
        for (int l = 0; l < MAXLEN; ++l) {
            int v = tx[l];                       // wave-uniform LDS broadcast
            len += (v != VOC);
            const float* gr = gram + v * VOC;    // row 96 = zeros
            a0 += gr[lane];
            a1 += (lane < 32) ? gr[64 + lane] : 0.f;
        }
        float dinv = 1.f / (float)(len > 0 ? len : 1);
        float t0 = fmaxf(a0 * dinv, 1e-6f);
        float t1 = (lane < 32) ? fmaxf(a1 * dinv, 1e-6f) : 0.f;
        float s = t0 + t1;
        for (int o = 32; o; o >>= 1) s += __shfl_xor(s, o);
        float inv = 1.f / s;
        float ts0 = t0 * inv, ts1 = t1 * inv;
        float c0 = ts0 * logf(ts0);
        float c1 = (lane < 32) ? ts1 * logf(ts1) : 0.f;
        float ent = c0 + c1;
        for (int o = 32; o; o >>= 1) ent += __shfl_xor(ent, o);
        s_stat[g][lane] = len ? ts0 : 0.f;
        if (lane < 32) s_stat[g][64 + lane] = len ? ts1 : 0.f;
        if (lane == 0) s_stat[g][VOC] = len ? ent : 100.f;
    }
    __syncthreads();

    // ---- KL: 320 threads, one (row,g) dot each
    if (tid < RPB * NGT) {
        int row = tid >> 5, g = tid & 31;
        const float* L = s_lp[row];              // 32 lanes same addr -> broadcast
        const float* S = s_stat[g];              // stride 97 -> conflict-free
        float d0 = 0.f, d1 = 0.f, d2 = 0.f, d3 = 0.f;
#pragma unroll
        for (int c = 0; c < VOC; c += 4) {
            d0 += L[c]     * S[c];
            d1 += L[c + 1] * S[c + 1];
            d2 += L[c + 2] * S[c + 2];
            d3 += L[c + 3] * S[c + 3];
        }
        s_ct[row][g] = fmaxf(S[VOC] - (d0 + d1 + d2 + d3), 0.f);
    }
    __syncthreads();

    // ---- joint L1 sweep: 1 col/thread, all 10 rows per tgtT read
    float acc[RPB];
#pragma unroll
    for (int r = 0; r < RPB; ++r) acc[r] = 0.f;
#pragma unroll 5
    for (int k = 0; k < NDIM; ++k) {
        float tv = tgtT[(k << 9) + tid];
#pragma unroll
        for (int r = 0; r < RPB; ++r) acc[r] += fabsf(s_pp[r][k] - tv);
    }

    int gb = tid >> 5, g = tid & 31;
    float text = (gb == b) ? 1.f : 0.f;
#pragma unroll
    for (int r = 0; r < RPB; ++r) {
        out[(size_t)(r0 + r) * NCOL + tid] = s_cc[r] + acc[r] + text * s_ct[r][g];
    }
}

extern "C" void kernel_launch(void* const* d_in, const int* in_sizes, int n_in,
                              void* d_out, int out_size, void* d_ws, size_t ws_size,
                              hipStream_t stream) {
    const float* pred_logits      = (const float*)d_in[0];
    const float* pred_ctrl_points = (const float*)d_in[1];
    const float* pred_text_logits = (const float*)d_in[2];
    const float* tgt_ctrl_points  = (const float*)d_in[3];
    const int*   target_texts     = (const int*)d_in[4];
    const float* centroids        = (const float*)d_in[5];
    float* out = (float*)d_out;
    float* ws  = (float*)d_ws;

    float* gram = ws + WS_GRAM;
    float* logp = ws + WS_LOGP;
    float* cc   = ws + WS_CC;
    float* tgtT = ws + WS_TGTT;

    k1_kernel<<<K1_BLKS, 128, 0, stream>>>(pred_logits, pred_text_logits, centroids,
                                           tgt_ctrl_points, gram, logp, cc, tgtT);
    k2_kernel<<<(BS * NQ) / RPB, 512, 0, stream>>>(pred_ctrl_points, tgtT, gram,
                                                   target_texts, logp, cc, out);
}